// Round 5
// baseline (2043.020 us; speedup 1.0000x reference)
//
#include <hip/hip_runtime.h>
#include <hip/hip_fp8.h>

#define T_DIM 2048
#define D_DIM 4096
#define I_DIM 11008

typedef int v8i __attribute__((ext_vector_type(8)));
typedef float v4f __attribute__((ext_vector_type(4)));

// ---------------------------------------------------------------------------
// Act quant: per-(row,128-block) amax -> scale -> fp8. One wave handles TWO
// 128-blocks (lane>>5 selects block, float4 per lane, 32-lane reduction).
// Scales stored TRANSPOSED: St[kb][t].
// ---------------------------------------------------------------------------
__global__ void quant_x_kernel(const float* __restrict__ X, unsigned char* __restrict__ Q,
                               float* __restrict__ St, const int T, const int D) {
  const int wave = (blockIdx.x << 2) + (threadIdx.x >> 6);
  const int lane = threadIdx.x & 63;
  const int qb = (wave << 1) + (lane >> 5);   // global quant-block id
  const int l = lane & 31;
  const int nb = D >> 7;
  const int t = qb / nb;
  const int kb = qb - t * nb;
  const size_t base = (size_t)t * D + ((size_t)kb << 7);
  const float4 v = ((const float4*)(X + base))[l];
  float a = fmaxf(fmaxf(fabsf(v.x), fabsf(v.y)), fmaxf(fabsf(v.z), fabsf(v.w)));
#pragma unroll
  for (int off = 16; off > 0; off >>= 1) a = fmaxf(a, __shfl_xor(a, off));
  const float scale = (a == 0.f) ? 1.f : (a / 448.f);
  const float inv = 1.f / scale;
  int r = __builtin_amdgcn_cvt_pk_fp8_f32(v.x * inv, v.y * inv, 0, false);
  r = __builtin_amdgcn_cvt_pk_fp8_f32(v.z * inv, v.w * inv, r, true);
  ((unsigned int*)(Q + base))[l] = (unsigned int)r;
  if (l == 0) St[(size_t)kb * T + t] = scale;
}

// ---------------------------------------------------------------------------
// silu(h1)*h3 then per-128-block quantization. Same 2-blocks-per-wave shape.
// ---------------------------------------------------------------------------
__global__ void silu_mul_quant_kernel(const float* __restrict__ H1, const float* __restrict__ H3,
                                      unsigned char* __restrict__ Q, float* __restrict__ St,
                                      const int T, const int D) {
  const int wave = (blockIdx.x << 2) + (threadIdx.x >> 6);
  const int lane = threadIdx.x & 63;
  const int qb = (wave << 1) + (lane >> 5);
  const int l = lane & 31;
  const int nb = D >> 7;
  const int t = qb / nb;
  const int kb = qb - t * nb;
  const size_t base = (size_t)t * D + ((size_t)kb << 7);
  const float4 v1 = ((const float4*)(H1 + base))[l];
  const float4 v3 = ((const float4*)(H3 + base))[l];
  float4 h;
  h.x = (v1.x / (1.f + __expf(-v1.x))) * v3.x;
  h.y = (v1.y / (1.f + __expf(-v1.y))) * v3.y;
  h.z = (v1.z / (1.f + __expf(-v1.z))) * v3.z;
  h.w = (v1.w / (1.f + __expf(-v1.w))) * v3.w;
  float a = fmaxf(fmaxf(fabsf(h.x), fabsf(h.y)), fmaxf(fabsf(h.z), fabsf(h.w)));
#pragma unroll
  for (int off = 16; off > 0; off >>= 1) a = fmaxf(a, __shfl_xor(a, off));
  const float scale = (a == 0.f) ? 1.f : (a / 448.f);
  const float inv = 1.f / scale;
  int r = __builtin_amdgcn_cvt_pk_fp8_f32(h.x * inv, h.y * inv, 0, false);
  r = __builtin_amdgcn_cvt_pk_fp8_f32(h.z * inv, h.w * inv, r, true);
  ((unsigned int*)(Q + base))[l] = (unsigned int)r;
  if (l == 0) St[(size_t)kb * T + t] = scale;
}

// ---------------------------------------------------------------------------
// Weight convert fp32 -> fp8 (values exactly representable). Grid-stride.
// ---------------------------------------------------------------------------
__global__ void convert_fp8_kernel(const float4* __restrict__ W, unsigned int* __restrict__ Q,
                                   const int n4) {
  const int stride = gridDim.x * 256;
  for (int i = blockIdx.x * 256 + threadIdx.x; i < n4; i += stride) {
    const float4 f = W[i];
    int r = __builtin_amdgcn_cvt_pk_fp8_f32(f.x, f.y, 0, false);
    r = __builtin_amdgcn_cvt_pk_fp8_f32(f.z, f.w, r, true);
    Q[i] = (unsigned int)r;
  }
}

// ---------------------------------------------------------------------------
// fp8 block-scaled GEMM. VGPR-staged (buffer_load -> ds_write), padded LDS
// stride 144B => conflict-free reads AND writes; buffer_loads for iter k+1
// remain IN FLIGHT across both barriers (no global_load_lds => no vmcnt(0)
// drain at s_barrier). 128x128 tile, BK=128, 4 waves of 64x64.
// ---------------------------------------------------------------------------
#define LSTR 144

template <int NKB>
__global__ __launch_bounds__(256, 2) void gemm_fp8_bs(
    const unsigned char* __restrict__ A, const float* __restrict__ sAt,
    const unsigned char* __restrict__ B, const float* __restrict__ sB,
    float* __restrict__ C, const int M, const int N) {
  const int K = NKB << 7;
  __shared__ unsigned char As[128 * LSTR];
  __shared__ unsigned char Bs[128 * LSTR];

  const int tid = threadIdx.x;
  const int lane = tid & 63;
  const int w = tid >> 6;
  const int wm = (w >> 1) << 6;
  const int wn = (w & 1) << 6;
  const int row16 = lane & 15;
  const int quad = lane >> 4;
  const int m0 = blockIdx.x << 7;
  const int n0 = blockIdx.y << 7;

  // staging: wave w covers rows [w*32, w*32+32); per t-step 8 rows.
  const int srow = (w << 5) + (lane >> 3);
  const int scol = (lane & 7) << 4;
  const unsigned char* gA = A + (size_t)(m0 + srow) * K + scol;
  const unsigned char* gB = B + (size_t)(n0 + srow) * K + scol;
  const int lofs = srow * LSTR + scol;

  v4f acc[4][4];
#pragma unroll
  for (int i = 0; i < 4; ++i)
#pragma unroll
    for (int j = 0; j < 4; ++j) acc[i][j] = (v4f){0.f, 0.f, 0.f, 0.f};

  const float* sArow = sAt + m0 + wm + (quad << 2);
  const float* sBrow = sB + (size_t)(n0 >> 7) * NKB;

  int4 ra[4], rb[4];
  float4 sa_c[4], sa_n[4];
  float sb_c, sb_n;

  // prologue: issue loads for kb=0
#pragma unroll
  for (int t = 0; t < 4; ++t) {
    ra[t] = *(const int4*)(gA + (size_t)(t * 8) * K);
    rb[t] = *(const int4*)(gB + (size_t)(t * 8) * K);
  }
  {
    const float4* sap = (const float4*)(sArow);
#pragma unroll
    for (int i = 0; i < 4; ++i) sa_c[i] = sap[i * 4];
    sb_c = sBrow[0];
  }

  for (int kb = 0; kb < NKB; ++kb) {
    __syncthreads();  // prior readers of LDS done (lgkm only)
    // VGPR -> LDS (waits vmcnt for loads issued a full iteration ago)
#pragma unroll
    for (int t = 0; t < 4; ++t) {
      *(int4*)(As + lofs + t * 8 * LSTR) = ra[t];
      *(int4*)(Bs + lofs + t * 8 * LSTR) = rb[t];
    }
    // issue next iteration's loads; stay outstanding across barrier+compute
    const int kn = (kb + 1 < NKB) ? kb + 1 : NKB - 1;
    {
      const size_t koff = (size_t)kn << 7;
#pragma unroll
      for (int t = 0; t < 4; ++t) {
        ra[t] = *(const int4*)(gA + (size_t)(t * 8) * K + koff);
        rb[t] = *(const int4*)(gB + (size_t)(t * 8) * K + koff);
      }
      const float4* sap = (const float4*)(sArow + (size_t)kn * M);
#pragma unroll
      for (int i = 0; i < 4; ++i) sa_n[i] = sap[i * 4];
      sb_n = sBrow[kn];
    }
    __syncthreads();  // ds_writes visible (lgkm only; vm loads still in flight)

    v4f zero = {0.f, 0.f, 0.f, 0.f};
    v8i a[4], b[4];
#pragma unroll
    for (int i = 0; i < 4; ++i) {
      const unsigned char* p = As + (wm + (i << 4) + row16) * LSTR + (quad << 5);
      union { v8i v; int4 h[2]; } u;
      u.h[0] = *(const int4*)(p);
      u.h[1] = *(const int4*)(p + 16);
      a[i] = u.v;
    }
#pragma unroll
    for (int j = 0; j < 4; ++j) {
      const unsigned char* p = Bs + (wn + (j << 4) + row16) * LSTR + (quad << 5);
      union { v8i v; int4 h[2]; } u;
      u.h[0] = *(const int4*)(p);
      u.h[1] = *(const int4*)(p + 16);
      b[j] = u.v;
    }

#pragma unroll
    for (int i = 0; i < 4; ++i) {
      v4f cs;
      cs.x = sa_c[i].x * sb_c; cs.y = sa_c[i].y * sb_c;
      cs.z = sa_c[i].z * sb_c; cs.w = sa_c[i].w * sb_c;
#pragma unroll
      for (int j = 0; j < 4; ++j) {
        v4f p = __builtin_amdgcn_mfma_scale_f32_16x16x128_f8f6f4(
            a[i], b[j], zero, 0, 0, 0, 0x7f7f7f7f, 0, 0x7f7f7f7f);
        acc[i][j] += cs * p;
      }
    }

#pragma unroll
    for (int i = 0; i < 4; ++i) sa_c[i] = sa_n[i];
    sb_c = sb_n;
  }

  // epilogue: C/D layout col=lane&15, row=quad*4+reg
#pragma unroll
  for (int i = 0; i < 4; ++i) {
    const size_t rbase = (size_t)(m0 + wm + (i << 4) + (quad << 2));
#pragma unroll
    for (int r = 0; r < 4; ++r) {
      float* crow = C + (rbase + r) * N + n0 + wn + row16;
#pragma unroll
      for (int j = 0; j < 4; ++j) crow[j << 4] = acc[i][j][r];
    }
  }
}

extern "C" void kernel_launch(void* const* d_in, const int* in_sizes, int n_in,
                              void* d_out, int out_size, void* d_ws, size_t ws_size,
                              hipStream_t stream) {
  const float* x   = (const float*)d_in[0];
  const float* w1q = (const float*)d_in[1];
  const float* w1s = (const float*)d_in[2];
  const float* w2q = (const float*)d_in[3];
  const float* w2s = (const float*)d_in[4];
  const float* w3q = (const float*)d_in[5];
  const float* w3s = (const float*)d_in[6];

  unsigned char* ws = (unsigned char*)d_ws;
  const size_t SZ_QX = (size_t)T_DIM * D_DIM;
  const size_t SZ_W  = (size_t)I_DIM * D_DIM;
  const size_t SZ_QH = (size_t)T_DIM * I_DIM;
  const size_t SZ_SX = (size_t)(D_DIM / 128) * T_DIM * 4;
  const size_t SZ_SH = (size_t)(I_DIM / 128) * T_DIM * 4;
  const size_t SZ_H  = (size_t)T_DIM * I_DIM * 4;

  unsigned char* qx   = ws;             ws += SZ_QX;
  unsigned char* w1q8 = ws;             ws += SZ_W;
  unsigned char* w3q8 = ws;             ws += SZ_W;
  unsigned char* w2q8 = ws;             ws += SZ_W;
  unsigned char* qh   = ws;             ws += SZ_QH;
  float* sxt = (float*)ws;              ws += SZ_SX;
  float* sht = (float*)ws;              ws += SZ_SH;
  float* h1  = (float*)ws;              ws += SZ_H;
  float* h3  = (float*)ws;              ws += SZ_H;

  // quant x: 65536 quant-blocks, 2 per wave, 8 per thread-block
  quant_x_kernel<<<(T_DIM * (D_DIM / 128)) / 8, 256, 0, stream>>>(x, qx, sxt, T_DIM, D_DIM);

  const int n4w = (int)(SZ_W / 4);
  convert_fp8_kernel<<<2048, 256, 0, stream>>>((const float4*)w1q, (unsigned int*)w1q8, n4w);
  convert_fp8_kernel<<<2048, 256, 0, stream>>>((const float4*)w3q, (unsigned int*)w3q8, n4w);
  convert_fp8_kernel<<<2048, 256, 0, stream>>>((const float4*)w2q, (unsigned int*)w2q8, n4w);

  dim3 g13(T_DIM / 128, I_DIM / 128);
  gemm_fp8_bs<D_DIM / 128><<<g13, 256, 0, stream>>>(qx, sxt, w1q8, w1s, h1, T_DIM, I_DIM);
  gemm_fp8_bs<D_DIM / 128><<<g13, 256, 0, stream>>>(qx, sxt, w3q8, w3s, h3, T_DIM, I_DIM);

  silu_mul_quant_kernel<<<(T_DIM * (I_DIM / 128)) / 8, 256, 0, stream>>>(h1, h3, qh, sht, T_DIM, I_DIM);

  dim3 g2(T_DIM / 128, D_DIM / 128);
  gemm_fp8_bs<I_DIM / 128><<<g2, 256, 0, stream>>>(qh, sht, w2q8, w2s, (float*)d_out, T_DIM, D_DIM);

  (void)in_sizes; (void)n_in; (void)out_size; (void)ws_size;
}